// Round 14
// baseline (37.077 us; speedup 1.0000x reference)
//
#include <hip/hip_runtime.h>

#define G_ 19
#define A_ 5
#define C_ 20
#define BS_ 16
#define N_ (G_*G_*A_)        // 1805
#define CHK 8                // segments (blocks) per batch
#define SEG 256              // slots per segment
#define NBLK (BS_*CHK)       // 128
#define EPSF 1e-8f

// ws byte offsets (16B-aligned blocks)
#define OFF_P1  0                               // float[128]  loss partials
#define OFF_CP  (OFF_P1 + NBLK*4)               // u32[128]  (padded pos counts)
#define OFF_CN  (OFF_CP + NBLK*4)               // u32[128]
#define OFF_PLB (OFF_CN + NBLK*4 + 4)           // pad to 16 -> float4[128*256]
#define OFF_PLA (OFF_PLB + NBLK*SEG*16)         // float[128*256]  (-0.6*area_g)
#define OFF_NLB (OFF_PLA + NBLK*SEG*4)          // float4[128*256]
#define OFF_NLV (OFF_NLB + NBLK*SEG*16)         // float[128*256]

__device__ __forceinline__ float sigmoidf_(float x) {
    return 1.0f / (1.0f + __expf(-x));
}

__global__ __launch_bounds__(256) void k1_elemwise(
    const float* __restrict__ pred, const float* __restrict__ gt,
    const float* __restrict__ anch, const int* __restrict__ epoch_p,
    char* __restrict__ ws, float* __restrict__ out)
{
    float*    partial1 = (float*)(ws + OFF_P1);
    unsigned* cntP  = (unsigned*)(ws + OFF_CP);
    unsigned* cntN  = (unsigned*)(ws + OFF_CN);
    float4*   plbox = (float4*)(ws + OFF_PLB);
    float*    plab  = (float*) (ws + OFF_PLA);
    float4*   nlbox = (float4*)(ws + OFF_NLB);
    float*    nlval = (float*) (ws + OFF_NLV);

    __shared__ __align__(16) float sp[256*25];   // 25.6 KB
    __shared__ __align__(16) float sg[256*25];   // 25.6 KB
    __shared__ float red[4];
    __shared__ int wpo[4], wno[4];

    const int tid  = threadIdx.x;
    const int lane = tid & 63, wid = tid >> 6;
    const int b    = blockIdx.y;
    const int ch   = blockIdx.x;
    const int blin = b * CHK + ch;

    if (blin == 0 && tid == 0) out[0] = 0.f;     // stream-ordered before k2's atomics

    int n0   = ch * 256;
    int rows = min(256, N_ - n0);
    const float* srcP = pred + ((size_t)b*N_ + n0)*25;
    const float* srcG = gt   + ((size_t)b*N_ + n0)*25;
    if (rows == 256) {
        #pragma unroll
        for (int k = 0; k < 25; k++) sp[tid + k*256] = srcP[tid + k*256];
        #pragma unroll
        for (int k = 0; k < 25; k++) sg[tid + k*256] = srcG[tid + k*256];
    } else {
        int ndw = rows * 25;
        for (int d = tid; d < ndw; d += 256) { sp[d] = srcP[d]; sg[d] = srcG[d]; }
    }
    __syncthreads();

    int n = n0 + tid;
    bool valid = tid < rows;
    const float* P = sp + tid*25;
    const float* T = sg + tid*25;
    float local = 0.f;

    bool pos = false;
    float gx1=0, gy1=0, gx2=0, gy2=0, area_g=0;
    float px1=0, py1=0, px2=0, py2=0, pconf=0;

    if (valid) {
        int a  = n % A_;
        int g2 = (n / A_) % G_;
        int g1 = n / (A_ * G_);
        float px = P[0], py = P[1], pw = P[2], ph = P[3], po = P[4];
        float gx = T[0], gy = T[1], gw = T[2], gh = T[3], go = T[4];
        float aw = anch[a*2+0], ah = anch[a*2+1];

        float sx  = sigmoidf_(px), sy = sigmoidf_(py);
        float pbw = __expf(pw) * aw, pbh = __expf(ph) * ah;
        float gbw = __expf(gw) * aw, gbh = __expf(gh) * ah;

        float cxp = sx + (float)g2, cyp = sy + (float)g1;
        float hwp = pbw * (0.5f * G_), hhp = pbh * (0.5f * G_);
        px1 = cxp - hwp; py1 = cyp - hhp; px2 = cxp + hwp; py2 = cyp + hhp;

        float cxg = gx + (float)g2, cyg = gy + (float)g1;
        float hwg = gbw * (0.5f * G_), hhg = gbh * (0.5f * G_);
        gx1 = cxg - hwg; gy1 = cyg - hhg; gx2 = cxg + hwg; gy2 = cyg + hhg;

        pconf = sigmoidf_(po);
        float area_p = fmaxf(px2 - px1, 0.f) * fmaxf(py2 - py1, 0.f);
        area_g = fmaxf(gx2 - gx1, 0.f) * fmaxf(gy2 - gy1, 0.f);

        if (*epoch_p < 12) {
            local += 0.01f * (px*px + py*py + pw*pw + ph*ph);
        }
        pos = go > 0.5f;
        if (pos) {
            float d0 = gx - sx, d1 = gy - sy, d2 = gw - pw, d3 = gh - ph;
            local += 5.0f * (d0*d0 + d1*d1 + d2*d2 + d3*d3);
            float ix1 = fmaxf(px1, gx1), iy1 = fmaxf(py1, gy1);
            float ix2 = fminf(px2, gx2), iy2 = fminf(py2, gy2);
            float iw = fmaxf(ix2 - ix1, 0.f), ih = fmaxf(iy2 - iy1, 0.f);
            float inter = iw * ih;
            float iou = inter / (area_p + area_g - inter + EPSF);
            float dc = iou - pconf;
            local += dc * dc;
            float cl[C_];
            float m = -1e30f;
            #pragma unroll
            for (int c = 0; c < C_; c++) { cl[c] = P[5+c]; m = fmaxf(m, cl[c]); }
            float s = 0.f;
            #pragma unroll
            for (int c = 0; c < C_; c++) { cl[c] = __expf(cl[c] - m); s += cl[c]; }
            float inv = 1.0f / s;
            float acc = 0.f;
            #pragma unroll
            for (int c = 0; c < C_; c++) { float d = T[5+c] - cl[c]*inv; acc += d*d; }
            local += acc;
        }
        local *= (1.0f / BS_);
    }

    // deterministic block-local compaction into this block's segment
    bool isPos = valid && pos;
    bool isNeg = valid && !pos;
    unsigned long long mp = __ballot(isPos);
    unsigned long long mn = __ballot(isNeg);
    unsigned long long ltm = (1ull << lane) - 1ull;
    int ppre = __popcll(mp & ltm);
    int npre = __popcll(mn & ltm);
    if (lane == 0) { wpo[wid] = __popcll(mp); wno[wid] = __popcll(mn); }
    __syncthreads();
    int pexc = 0, nexc = 0, tp = 0, tn = 0;
    #pragma unroll
    for (int w = 0; w < 4; w++) {
        if (w < wid) { pexc += wpo[w]; nexc += wno[w]; }
        tp += wpo[w]; tn += wno[w];
    }
    if (isPos) {
        int k = blin*SEG + pexc + ppre;
        plbox[k] = make_float4(gx1, gy1, gx2, gy2);
        plab[k]  = -0.6f * area_g;                 // pre-scaled for k2's fma
    } else if (isNeg) {
        int k = blin*SEG + nexc + npre;
        nlbox[k] = make_float4(px1, py1, px2, py2);
        nlval[k] = (0.5f / BS_) * pconf * pconf;
    }
    // pad pos list to a multiple of 4 with inert dummies (inter=0, a06=-3e38)
    int padTo = (tp + 3) & ~3;                     // <= 256 always
    if (tid >= tp && tid < padTo) {
        plbox[blin*SEG + tid] = make_float4(3e8f, 3e8f, 3e8f, 3e8f);
        plab [blin*SEG + tid] = -3e38f;
    }
    if (tid == 0) { cntP[blin] = (unsigned)padTo; cntN[blin] = (unsigned)tn; }

    // block loss partial
    for (int off = 32; off; off >>= 1) local += __shfl_down(local, off);
    if (lane == 0) red[wid] = local;
    __syncthreads();
    if (tid == 0) partial1[blin] = red[0] + red[1] + red[2] + red[3];
}

// k2_fused: one block per neg segment (8 iseg x 16 b = 128 blocks, 512 thr).
// Wave w scans pos segment w only (113-j serial path, same as R13-k2);
// each lane owns 4 i-boxes (ILP-4: 352cy VALU per 4-j group > ~200cy scalar
// latency -> hidden). LDS combine of 8 wave-partials, in-block noobj sum,
// partial1 fold, 1 atomicAdd per block. No flags, no k3 node.
__global__ __launch_bounds__(512) void k2_fused(char* __restrict__ ws,
                                                float* __restrict__ out)
{
    const float*    partial1 = (const float*)(ws + OFF_P1);
    const unsigned* cntP  = (const unsigned*)(ws + OFF_CP);
    const unsigned* cntN  = (const unsigned*)(ws + OFF_CN);
    const float4*   plbox = (const float4*)(ws + OFF_PLB);
    const float*    plab  = (const float*) (ws + OFF_PLA);
    const float4*   nlbox = (const float4*)(ws + OFF_NLB);
    const float*    nlval = (const float*) (ws + OFF_NLV);

    const int tid  = threadIdx.x;
    const int il   = tid & 63;
    const int w    = __builtin_amdgcn_readfirstlane(tid >> 6);  // wave 0..7
    const int iseg = blockIdx.x;        // 0..7
    const int b    = blockIdx.y;        // 0..15
    const int iblin = b*CHK + iseg;

    __shared__ float smd[8*256];        // 8 KB  [wave][islot]
    __shared__ float st0[256];          // 1 KB
    __shared__ float red[8];

    // 4 i-boxes per lane: islot = il + 64*k
    float4 p[4]; float t0[4]; float md[4];
    #pragma unroll
    for (int k = 0; k < 4; k++) {
        p[k]  = nlbox[iblin*SEG + il + 64*k];     // stale-slot-safe (gated later)
        t0[k] = 0.6f * ((p[k].z - p[k].x) * (p[k].w - p[k].y) + EPSF);
        md[k] = -3e38f;
    }

    // this wave's pos segment (block-uniform per wave; scalar loads)
    const int jblin = b*CHK + w;
    const int jlen  = (int)cntP[jblin];           // multiple of 4 (padded)
    const float4* jb = plbox + jblin*SEG;
    const float*  ja = plab  + jblin*SEG;

    for (int j = 0; j < jlen; j += 4) {
        #pragma unroll
        for (int t = 0; t < 4; t++) {
            float4 g  = jb[j + t];                // s_load (wave-uniform)
            float a06 = ja[j + t];
            #pragma unroll
            for (int k = 0; k < 4; k++) {
                float ax = fmaxf(p[k].x, g.x), ay = fmaxf(p[k].y, g.y);
                float bx = fminf(p[k].z, g.z), by = fminf(p[k].w, g.w);
                float in0 = fmaxf(bx - ax, 0.f) * fmaxf(by - ay, 0.f);
                md[k] = fmaxf(md[k], fmaf(1.6f, in0, a06));  // 1.6*inter - 0.6*area_b
            }
        }
    }

    #pragma unroll
    for (int k = 0; k < 4; k++) smd[w*256 + il + 64*k] = md[k];
    if (w == 0) {
        #pragma unroll
        for (int k = 0; k < 4; k++) st0[il + 64*k] = t0[k];
    }
    __syncthreads();

    const int nn = (int)cntN[iblin];
    float v = 0.f;
    if (tid < 256) {
        float m0 = smd[tid];
        #pragma unroll
        for (int q = 1; q < 8; q++) m0 = fmaxf(m0, smd[q*256 + tid]);
        // kept (noobj) <=> NOT (iou >= 0.6) <=> m0 < 0.6*(area_a+eps)
        if (tid < nn && m0 < st0[tid]) v = nlval[iblin*SEG + tid];
        if (tid == 0) v += partial1[iblin];
    }
    for (int off = 32; off; off >>= 1) v += __shfl_down(v, off);
    int wid2 = tid >> 6, lane2 = tid & 63;
    if (lane2 == 0) red[wid2] = v;
    __syncthreads();
    if (tid == 0) {
        float s = 0.f;
        #pragma unroll
        for (int q = 0; q < 8; q++) s += red[q];
        atomicAdd(out, s);
    }
}

extern "C" void kernel_launch(void* const* d_in, const int* in_sizes, int n_in,
                              void* d_out, int out_size, void* d_ws, size_t ws_size,
                              hipStream_t stream) {
    const float* pred  = (const float*)d_in[0];
    const float* gt_   = (const float*)d_in[1];
    const float* anch  = (const float*)d_in[2];
    const int*   epoch = (const int*)d_in[3];
    float* out = (float*)d_out;
    char*  ws  = (char*)d_ws;

    dim3 g1(CHK, BS_);
    k1_elemwise<<<g1, 256, 0, stream>>>(pred, gt_, anch, epoch, ws, out);
    dim3 g2(CHK, BS_);
    k2_fused<<<g2, 512, 0, stream>>>(ws, out);
}

// Round 15
// 23.073 us; speedup vs baseline: 1.6069x; 1.6069x over previous
//
#include <hip/hip_runtime.h>

#define G_ 19
#define A_ 5
#define C_ 20
#define BS_ 16
#define N_ (G_*G_*A_)        // 1805
#define CHK 8                // segments (blocks) per batch
#define SEG 256              // slots per segment
#define NBLK (BS_*CHK)       // 128
#define EPSF 1e-8f

// ws byte offsets (16B-aligned blocks)
#define OFF_P1  0                               // float[128]  loss partials
#define OFF_CP  (OFF_P1 + NBLK*4)               // u32[128]  (padded pos counts)
#define OFF_CN  (OFF_CP + NBLK*4)               // u32[128]
#define OFF_PLB (OFF_CN + NBLK*4 + 4)           // pad to 16 -> float4[128*256]
#define OFF_PLA (OFF_PLB + NBLK*SEG*16)         // float[128*256]  (-0.6*area_g)
#define OFF_NLB (OFF_PLA + NBLK*SEG*4)          // float4[128*256]
#define OFF_NLV (OFF_NLB + NBLK*SEG*16)         // float[128*256]
#define OFF_FLG (OFF_NLV + NBLK*SEG*4)          // u32[128*256]

__device__ __forceinline__ float sigmoidf_(float x) {
    return 1.0f / (1.0f + __expf(-x));
}

__global__ __launch_bounds__(256) void k1_elemwise(
    const float* __restrict__ pred, const float* __restrict__ gt,
    const float* __restrict__ anch, const int* __restrict__ epoch_p,
    char* __restrict__ ws, float* __restrict__ out)
{
    float*    partial1 = (float*)(ws + OFF_P1);
    unsigned* cntP  = (unsigned*)(ws + OFF_CP);
    unsigned* cntN  = (unsigned*)(ws + OFF_CN);
    float4*   plbox = (float4*)(ws + OFF_PLB);
    float*    plab  = (float*) (ws + OFF_PLA);
    float4*   nlbox = (float4*)(ws + OFF_NLB);
    float*    nlval = (float*) (ws + OFF_NLV);
    unsigned* flags = (unsigned*)(ws + OFF_FLG);

    __shared__ __align__(16) float sp[256*25];   // 25.6 KB
    __shared__ __align__(16) float sg[256*25];   // 25.6 KB
    __shared__ float red[4];
    __shared__ int wpo[4], wno[4];

    const int tid  = threadIdx.x;
    const int lane = tid & 63, wid = tid >> 6;
    const int b    = blockIdx.y;
    const int ch   = blockIdx.x;
    const int blin = b * CHK + ch;

    flags[blin*SEG + tid] = 0u;
    if (blin == 0 && tid == 0) out[0] = 0.f;     // stream-ordered before k3's atomics

    int n0   = ch * 256;
    int rows = min(256, N_ - n0);
    const float* srcP = pred + ((size_t)b*N_ + n0)*25;
    const float* srcG = gt   + ((size_t)b*N_ + n0)*25;
    if (rows == 256) {
        #pragma unroll
        for (int k = 0; k < 25; k++) sp[tid + k*256] = srcP[tid + k*256];
        #pragma unroll
        for (int k = 0; k < 25; k++) sg[tid + k*256] = srcG[tid + k*256];
    } else {
        int ndw = rows * 25;
        for (int d = tid; d < ndw; d += 256) { sp[d] = srcP[d]; sg[d] = srcG[d]; }
    }
    __syncthreads();

    int n = n0 + tid;
    bool valid = tid < rows;
    const float* P = sp + tid*25;
    const float* T = sg + tid*25;
    float local = 0.f;

    bool pos = false;
    float gx1=0, gy1=0, gx2=0, gy2=0, area_g=0;
    float px1=0, py1=0, px2=0, py2=0, pconf=0;

    if (valid) {
        int a  = n % A_;
        int g2 = (n / A_) % G_;
        int g1 = n / (A_ * G_);
        float px = P[0], py = P[1], pw = P[2], ph = P[3], po = P[4];
        float gx = T[0], gy = T[1], gw = T[2], gh = T[3], go = T[4];
        float aw = anch[a*2+0], ah = anch[a*2+1];

        float sx  = sigmoidf_(px), sy = sigmoidf_(py);
        float pbw = __expf(pw) * aw, pbh = __expf(ph) * ah;
        float gbw = __expf(gw) * aw, gbh = __expf(gh) * ah;

        float cxp = sx + (float)g2, cyp = sy + (float)g1;
        float hwp = pbw * (0.5f * G_), hhp = pbh * (0.5f * G_);
        px1 = cxp - hwp; py1 = cyp - hhp; px2 = cxp + hwp; py2 = cyp + hhp;

        float cxg = gx + (float)g2, cyg = gy + (float)g1;
        float hwg = gbw * (0.5f * G_), hhg = gbh * (0.5f * G_);
        gx1 = cxg - hwg; gy1 = cyg - hhg; gx2 = cxg + hwg; gy2 = cyg + hhg;

        pconf = sigmoidf_(po);
        float area_p = fmaxf(px2 - px1, 0.f) * fmaxf(py2 - py1, 0.f);
        area_g = fmaxf(gx2 - gx1, 0.f) * fmaxf(gy2 - gy1, 0.f);

        if (*epoch_p < 12) {
            local += 0.01f * (px*px + py*py + pw*pw + ph*ph);
        }
        pos = go > 0.5f;
        if (pos) {
            float d0 = gx - sx, d1 = gy - sy, d2 = gw - pw, d3 = gh - ph;
            local += 5.0f * (d0*d0 + d1*d1 + d2*d2 + d3*d3);
            float ix1 = fmaxf(px1, gx1), iy1 = fmaxf(py1, gy1);
            float ix2 = fminf(px2, gx2), iy2 = fminf(py2, gy2);
            float iw = fmaxf(ix2 - ix1, 0.f), ih = fmaxf(iy2 - iy1, 0.f);
            float inter = iw * ih;
            float iou = inter / (area_p + area_g - inter + EPSF);
            float dc = iou - pconf;
            local += dc * dc;
            float cl[C_];
            float m = -1e30f;
            #pragma unroll
            for (int c = 0; c < C_; c++) { cl[c] = P[5+c]; m = fmaxf(m, cl[c]); }
            float s = 0.f;
            #pragma unroll
            for (int c = 0; c < C_; c++) { cl[c] = __expf(cl[c] - m); s += cl[c]; }
            float inv = 1.0f / s;
            float acc = 0.f;
            #pragma unroll
            for (int c = 0; c < C_; c++) { float d = T[5+c] - cl[c]*inv; acc += d*d; }
            local += acc;
        }
        local *= (1.0f / BS_);
    }

    // deterministic block-local compaction into this block's segment
    bool isPos = valid && pos;
    bool isNeg = valid && !pos;
    unsigned long long mp = __ballot(isPos);
    unsigned long long mn = __ballot(isNeg);
    unsigned long long ltm = (1ull << lane) - 1ull;
    int ppre = __popcll(mp & ltm);
    int npre = __popcll(mn & ltm);
    if (lane == 0) { wpo[wid] = __popcll(mp); wno[wid] = __popcll(mn); }
    __syncthreads();
    int pexc = 0, nexc = 0, tp = 0, tn = 0;
    #pragma unroll
    for (int w = 0; w < 4; w++) {
        if (w < wid) { pexc += wpo[w]; nexc += wno[w]; }
        tp += wpo[w]; tn += wno[w];
    }
    if (isPos) {
        int k = blin*SEG + pexc + ppre;
        plbox[k] = make_float4(gx1, gy1, gx2, gy2);
        plab[k]  = -0.6f * area_g;                 // pre-scaled for k2's fma
    } else if (isNeg) {
        int k = blin*SEG + nexc + npre;
        nlbox[k] = make_float4(px1, py1, px2, py2);
        nlval[k] = (0.5f / BS_) * pconf * pconf;
    }
    // pad pos list to a multiple of 8 with inert dummies (inter=0, a06=-3e38)
    int padTo = (tp + 7) & ~7;                     // <= 256 always
    if (tid >= tp && tid < padTo) {
        plbox[blin*SEG + tid] = make_float4(3e8f, 3e8f, 3e8f, 3e8f);
        plab [blin*SEG + tid] = -3e38f;
    }
    if (tid == 0) { cntP[blin] = (unsigned)padTo; cntN[blin] = (unsigned)tn; }

    // block loss partial
    for (int off = 32; off; off >>= 1) local += __shfl_down(local, off);
    if (lane == 0) red[wid] = local;
    __syncthreads();
    if (tid == 0) partial1[blin] = red[0] + red[1] + red[2] + red[3];
}

// k2: j-operands are wave-uniform -> SGPR broadcast via scalar loads,
// 8-wide unrolled groups (one lgkmcnt drain per 8 j). No LDS, no atomics,
// no syncs. i compacted across the block's 2 neg segments.
// Grid (jc 8, ip 4, b 16) = 512 blocks x 256 thr.
__global__ __launch_bounds__(256) void k2_pairmax(char* __restrict__ ws)
{
    const unsigned* cntP  = (const unsigned*)(ws + OFF_CP);
    const unsigned* cntN  = (const unsigned*)(ws + OFF_CN);
    const float4*   plbox = (const float4*)(ws + OFF_PLB);
    const float*    plab  = (const float*) (ws + OFF_PLA);
    const float4*   nlbox = (const float4*)(ws + OFF_NLB);
    unsigned*       flags = (unsigned*)(ws + OFF_FLG);

    const int tid = threadIdx.x;
    const int jc  = blockIdx.x;         // 0..7  pos segment
    const int ip  = blockIdx.y;         // 0..3  pair of neg segments
    const int b   = blockIdx.z;

    const int jblin  = b*CHK + jc;
    const int iblin0 = b*CHK + ip*2;
    const int iblin1 = iblin0 + 1;

    const int jlen = (int)cntP[jblin];  // multiple of 8 (padded)
    if (jlen <= 0) return;              // uniform exit

    // compacted i across the two segments
    const int tn0 = (int)cntN[iblin0];
    const int tn1 = (int)cntN[iblin1];
    const bool valid = tid < tn0 + tn1;
    const int  seg  = (tid < tn0) ? iblin0 : iblin1;
    const int  k    = (tid < tn0) ? tid : tid - tn0;
    float4 p = nlbox[seg*SEG + min(k, 255)];
    float t0 = 0.6f * ((p.z - p.x) * (p.w - p.y) + EPSF);

    // wave-uniform j base (SGPR); loop var uniform -> scalar loads
    const int jbase = __builtin_amdgcn_readfirstlane(jblin * SEG);
    const float4* jb = plbox + jbase;
    const float*  ja = plab  + jbase;

    float md = -3e38f;
    for (int j = 0; j < jlen; j += 8) {
        #pragma unroll
        for (int t = 0; t < 8; t++) {
            float4 g = jb[j + t];                  // s_load_dwordx4 (uniform)
            float a06 = ja[j + t];                 // s_load_dword
            float ax = fmaxf(p.x, g.x), ay = fmaxf(p.y, g.y);
            float bx = fminf(p.z, g.z), by = fminf(p.w, g.w);
            float in0 = fmaxf(bx - ax, 0.f) * fmaxf(by - ay, 0.f);
            md = fmaxf(md, fmaf(1.6f, in0, a06));  // 1.6*inter - 0.6*area_b
        }
    }
    // exceeded <=> iou >= 0.6 <=> md >= 0.6*(area_a+eps)
    if (valid && md >= t0) flags[seg*SEG + k] = 1u;   // benign same-value race
}

__global__ __launch_bounds__(256) void k3_final(char* __restrict__ ws,
                                                float* __restrict__ out)
{
    const float*    partial1 = (const float*)(ws + OFF_P1);
    const unsigned* cntN  = (const unsigned*)(ws + OFF_CN);
    const float*    nlval = (const float*) (ws + OFF_NLV);
    const unsigned* flags = (const unsigned*)(ws + OFF_FLG);

    const int tid  = threadIdx.x;
    const int blin = blockIdx.x;
    const int lane = tid & 63, wid = tid >> 6;

    float v = 0.f;
    if (tid < (int)cntN[blin] && flags[blin*SEG + tid] == 0u)
        v = nlval[blin*SEG + tid];
    if (tid == 0) v += partial1[blin];

    for (int off = 32; off; off >>= 1) v += __shfl_down(v, off);
    __shared__ float red[4];
    if (lane == 0) red[wid] = v;
    __syncthreads();
    if (tid == 0) atomicAdd(out, red[0] + red[1] + red[2] + red[3]);
}

extern "C" void kernel_launch(void* const* d_in, const int* in_sizes, int n_in,
                              void* d_out, int out_size, void* d_ws, size_t ws_size,
                              hipStream_t stream) {
    const float* pred  = (const float*)d_in[0];
    const float* gt_   = (const float*)d_in[1];
    const float* anch  = (const float*)d_in[2];
    const int*   epoch = (const int*)d_in[3];
    float* out = (float*)d_out;
    char*  ws  = (char*)d_ws;

    dim3 g1(CHK, BS_);
    k1_elemwise<<<g1, 256, 0, stream>>>(pred, gt_, anch, epoch, ws, out);
    dim3 g2(CHK, CHK/2, BS_);
    k2_pairmax<<<g2, 256, 0, stream>>>(ws);
    k3_final<<<NBLK, 256, 0, stream>>>(ws, out);
}